// Round 1
// 846.739 us; speedup vs baseline: 2.2230x; 2.2230x over previous
//
#include <hip/hip_runtime.h>

#define TT 32

// ---------- bf16 helpers (OCP bfloat16, RNE) ----------
__device__ __forceinline__ float bf16_bits_to_f32(unsigned short u) {
    unsigned v = ((unsigned)u) << 16; float f; __builtin_memcpy(&f, &v, 4); return f;
}
__device__ __forceinline__ unsigned short f32_to_bf16_rne(float f) {
    unsigned u; __builtin_memcpy(&u, &f, 4);
    u += 0x7FFFu + ((u >> 16) & 1u);            // round-to-nearest-even
    return (unsigned short)(u >> 16);
}
__device__ __forceinline__ float round_bf16_f32(float f) {  // f32 -> bf16 -> f32 value
    return bf16_bits_to_f32(f32_to_bf16_rne(f));
}
// Correctly-rounded f64 -> bf16 (single rounding): round-to-odd to f32, then RNE.
__device__ __forceinline__ float f64_to_bf16_f32(double d) {
    float fz = __double2float_rz(d);
    if ((double)fz != d) {
        unsigned u; __builtin_memcpy(&u, &fz, 4); u |= 1u; __builtin_memcpy(&fz, &u, 4);
    }
    return round_bf16_f32(fz);
}
// Build f64 from two u32 halves (register-pair construction, no memory).
__device__ __forceinline__ double d_from_halves(unsigned hi, unsigned lo) {
    unsigned long long u = ((unsigned long long)hi << 32) | (unsigned long long)lo;
    double d; __builtin_memcpy(&d, &u, 8); return d;
}

// ---------- dtype detect + init ----------
// fp32 spike words are exactly {0, 0x3F800000}. bf16-pair words hit other
// patterns with P=0.3/word -> P(misclassify bf16 as f32) = 0.7^64 ~ 1e-10.
__global__ void detect_and_init(const unsigned* __restrict__ spk,
                                int* __restrict__ flag, float* __restrict__ sums)
{
    unsigned w = spk[threadIdx.x];
    bool ok = (w == 0u) || (w == 0x3F800000u);
    unsigned long long vote = __ballot(ok);
    if (threadIdx.x == 0) {
        flag[0] = (vote == 0xFFFFFFFFFFFFFFFFull) ? 0 : 1;  // 0=f32, 1=bf16
        sums[0] = 0.f; sums[1] = 0.f; sums[2] = 0.f;
    }
}

// ---------- bit-pack layer-1 input spikes: one u32 mask (T=32) per site ----------
__global__ __launch_bounds__(256)
void pack_input(const void* __restrict__ ginv, unsigned* __restrict__ omask,
                int total, const int* __restrict__ flag)
{
    const int gid = blockIdx.x * 256 + threadIdx.x;
    if (gid >= total) return;
    unsigned mask = 0u;
    if (flag[0]) {
        const uint4* p = (const uint4*)((const unsigned short*)ginv + (size_t)gid * TT);
        #pragma unroll
        for (int q = 0; q < 4; ++q) {
            uint4 a = p[q];
            unsigned wd[4] = {a.x, a.y, a.z, a.w};
            #pragma unroll
            for (int m = 0; m < 4; ++m) {
                const int t = q * 8 + m * 2;
                mask |= (wd[m] & 0xFFFFu) ? (1u << t)       : 0u;
                mask |= (wd[m] >> 16)     ? (1u << (t + 1)) : 0u;
            }
        }
    } else {
        const float4* p = (const float4*)((const float*)ginv + (size_t)gid * TT);
        #pragma unroll
        for (int j = 0; j < 8; ++j) {
            float4 v = p[j];
            mask |= (v.x != 0.f) ? (1u << (j * 4 + 0)) : 0u;
            mask |= (v.y != 0.f) ? (1u << (j * 4 + 1)) : 0u;
            mask |= (v.z != 0.f) ? (1u << (j * 4 + 2)) : 0u;
            mask |= (v.w != 0.f) ? (1u << (j * 4 + 3)) : 0u;
        }
    }
    omask[gid] = mask;
}

// ---------- fused ConvT(stride2,k3,pad1, w*2) + CUBA scan, mask-path only ----------
// Grid: x = site chunk within parity class, y = co, z = parity class (po*2+pw).
// Parity-static taps (all compile-structured, register-resident):
//   even o: x[o/2]*w[1];  odd o: x[(o-1)/2]*w[2] + x[(o+1)/2]*w[0].
// z accumulated exactly in f64; addend built branchlessly as (sext(bit) & wv).
template<int CIN, int COUT, bool LAST>
__global__ __launch_bounds__(256)
void cuba_layer(const unsigned* __restrict__ inMask, const void* __restrict__ wptr,
                void* __restrict__ goutv, unsigned* __restrict__ outMask,
                int N, int Hi, int Wi, float* __restrict__ sumOut,
                const int* __restrict__ flag)
{
    const bool isbf = (flag[0] != 0);
    const int Ho = 2 * Hi - 1, Wo = 2 * Wi - 1;
    const int co = (int)blockIdx.y;
    const int po = (int)(blockIdx.z >> 1), pw = (int)(blockIdx.z & 1);
    const int nH = Hi - po, nW = Wi - pw;       // #oh / #ow values in this class
    const int spc = N * nH * nW;                // sites in this class (per co)
    const int gid2 = (int)blockIdx.x * 256 + (int)threadIdx.x;

    float cnt = 0.f;
    if (gid2 < spc) {
        const int b  = gid2 % nW;
        const int t1 = gid2 / nW;
        const int a  = t1 % nH;
        const int n  = t1 / nH;
        const int oh = 2 * a + po, ow = 2 * b + pw;
        const int planeSites = Hi * Wi;

        // Static taps (bounds-safe: po=1 -> a <= Hi-2, pw=1 -> b <= Wi-2).
        const int kwA = pw ? 2 : 1;
        const int khA = po ? 2 : 1;
        const int siteA = a * Wi + b,             wofA = khA * 3 + kwA; // always
        const int siteB = a * Wi + (b + 1),       wofB = khA * 3;       // iff pw
        const int siteC = (a + 1) * Wi + b,       wofC = kwA;           // iff po
        const int siteD = (a + 1) * Wi + (b + 1), wofD = 0;             // iff po&&pw

        double acc[TT];
        #pragma unroll
        for (int t = 0; t < TT; ++t) acc[t] = 0.0;

        const unsigned short* w16 = (const unsigned short*)wptr;
        const float* w32 = (const float*)wptr;

        for (int cin = 0; cin < CIN; ++cin) {
            const int sBase = (n * CIN + cin) * planeSites;
            const int wbase = (cin * COUT + co) * 9;

            auto addTap = [&](int site, int wof) {
                // weight_scale=2 folded: *2 exact in bf16 and f32.
                const float wraw = isbf ? bf16_bits_to_f32(w16[wbase + wof])
                                        : w32[wbase + wof];
                const double wv = 2.0 * (double)wraw;
                unsigned long long wb; __builtin_memcpy(&wb, &wv, 8);
                const unsigned wlo = (unsigned)wb, whi = (unsigned)(wb >> 32);
                const unsigned m = inMask[sBase + site];
                #pragma unroll
                for (int t = 0; t < TT; ++t) {
                    // sx = 0 or 0xFFFFFFFF from bit t of m (sign-extended bitfield)
                    const unsigned sx = (unsigned)(((int)(m << (31 - t))) >> 31);
                    acc[t] += d_from_halves(whi & sx, wlo & sx);
                }
            };

            addTap(siteA, wofA);
            if (pw) addTap(siteB, wofB);            // block-uniform branch
            if (po) {
                addTap(siteC, wofC);
                if (pw) addTap(siteD, wofD);
            }
        }

        // CUBA scan.
        unsigned mask = 0u;
        if (isbf) {
            // bf16 semantics: every add rounds to bf16; *0.5 and reset exact.
            float cur = 0.f, vol = 0.f;
            #pragma unroll
            for (int t = 0; t < TT; ++t) {
                const float z = f64_to_bf16_f32(acc[t]);      // conv output in bf16
                cur = round_bf16_f32(0.5f * cur + z);
                vol = round_bf16_f32(0.5f * vol + cur);
                const bool fire = (vol >= 1.0f);
                mask |= fire ? (1u << t) : 0u;
                vol = fire ? 0.f : vol;
            }
        } else {
            double cur = 0.0, vol = 0.0;
            #pragma unroll
            for (int t = 0; t < TT; ++t) {
                cur = fma(0.5, cur, acc[t]);
                vol = fma(0.5, vol, cur);
                const bool fire = (vol >= 1.0);
                mask |= fire ? (1u << t) : 0u;
                vol = fire ? 0.0 : vol;
            }
        }
        cnt = (float)__popc(mask);

        const int gidOut = ((n * COUT + co) * Ho + oh) * Wo + ow;
        if (LAST) {
            if (isbf) {
                uint4* ob = (uint4*)((unsigned short*)goutv + (size_t)gidOut * TT);
                #pragma unroll
                for (int q = 0; q < 4; ++q) {
                    unsigned wd[4];
                    #pragma unroll
                    for (int m2 = 0; m2 < 4; ++m2) {
                        const int t = (q * 4 + m2) * 2;
                        wd[m2] = (((mask >> t) & 1u) ? 0x3F80u : 0u)
                               | (((mask >> (t + 1)) & 1u) ? 0x3F800000u : 0u);
                    }
                    ob[q] = make_uint4(wd[0], wd[1], wd[2], wd[3]);
                }
            } else {
                float4* ob = (float4*)((float*)goutv + (size_t)gidOut * TT);
                #pragma unroll
                for (int j = 0; j < 8; ++j) {
                    float4 s4;
                    s4.x = (mask >> (j * 4 + 0)) & 1u ? 1.0f : 0.0f;
                    s4.y = (mask >> (j * 4 + 1)) & 1u ? 1.0f : 0.0f;
                    s4.z = (mask >> (j * 4 + 2)) & 1u ? 1.0f : 0.0f;
                    s4.w = (mask >> (j * 4 + 3)) & 1u ? 1.0f : 0.0f;
                    ob[j] = s4;
                }
            }
        } else {
            outMask[gidOut] = mask;
        }
    }

    // Wave-level (64) count reduction; per-layer sums are integers < 2^24 so
    // fp32 atomic accumulation is exact.
    #pragma unroll
    for (int o = 32; o >= 1; o >>= 1) cnt += __shfl_down(cnt, o);
    if ((threadIdx.x & 63) == 0 && cnt > 0.f) atomicAdd(sumOut, cnt);
}

__global__ void finalize_counts(const float* __restrict__ sums,
                                void* __restrict__ out, const int* __restrict__ flag)
{
    int i = threadIdx.x;
    if (i < 3) {
        const float numel[3] = {7872512.f, 15239168.f, 3748096.f};
        float v = sums[i] / numel[i];
        if (flag[0]) ((unsigned short*)out)[3748096 + i] = f32_to_bf16_rne(v);
        else         ((float*)out)[3748096 + i] = v;
    }
}

extern "C" void kernel_launch(void* const* d_in, const int* in_sizes, int n_in,
                              void* d_out, int out_size, void* d_ws, size_t ws_size,
                              hipStream_t stream)
{
    const void* x  = d_in[0];  // [4,128,16,16,32] spikes (f32 or bf16)
    const void* w1 = d_in[1];  // [128,64,3,3]
    const void* w2 = d_in[2];  // [64,32,3,3]
    const void* w3 = d_in[3];  // [32,2,3,3]

    // Bit-packed masks: input + both intermediates. Total ws ~ 3.42 MB.
    unsigned* buf0 = (unsigned*)d_ws;          // 4*128*16*16 = 131,072 words
    unsigned* buf1 = buf0 + 131072;            // 4*64*31*31  = 246,016 words
    unsigned* buf2 = buf1 + 246016;            // 4*32*61*61  = 476,288 words
    float* sums = (float*)(buf2 + 476288);     // 3 floats
    int*   flag = (int*)(sums + 3);

    detect_and_init<<<1, 64, 0, stream>>>((const unsigned*)x, flag, sums);
    pack_input<<<512, 256, 0, stream>>>(x, buf0, 131072, flag);

    // Grid: x = site chunk (max class: 4*Hi*Wi sites), y = co, z = parity class.
    // L1: 128->64, 16x16 -> 31x31. ceil(4*16*16/256)=4
    cuba_layer<128, 64, false><<<dim3(4, 64, 4), 256, 0, stream>>>(
        buf0, w1, nullptr, buf1, 4, 16, 16, sums + 0, flag);
    // L2: 64->32, 31x31 -> 61x61. ceil(4*31*31/256)=16
    cuba_layer<64, 32, false><<<dim3(16, 32, 4), 256, 0, stream>>>(
        buf1, w2, nullptr, buf2, 4, 31, 31, sums + 1, flag);
    // L3: 32->2, 61x61 -> 121x121. ceil(4*61*61/256)=59
    cuba_layer<32, 2, true><<<dim3(59, 2, 4), 256, 0, stream>>>(
        buf2, w3, d_out, nullptr, 4, 61, 61, sums + 2, flag);

    finalize_counts<<<1, 64, 0, stream>>>(sums, d_out, flag);
}

// Round 2
// 475.686 us; speedup vs baseline: 3.9570x; 1.7800x over previous
//
#include <hip/hip_runtime.h>

#define TT 32

// ---------- bf16 helpers (OCP bfloat16, RNE) ----------
__device__ __forceinline__ float bf16_bits_to_f32(unsigned short u) {
    unsigned v = ((unsigned)u) << 16; float f; __builtin_memcpy(&f, &v, 4); return f;
}
__device__ __forceinline__ unsigned short f32_to_bf16_rne(float f) {
    unsigned u; __builtin_memcpy(&u, &f, 4);
    u += 0x7FFFu + ((u >> 16) & 1u);            // round-to-nearest-even
    return (unsigned short)(u >> 16);
}
__device__ __forceinline__ float round_bf16_f32(float f) {  // f32 -> bf16 -> f32 value
    return bf16_bits_to_f32(f32_to_bf16_rne(f));
}
// Correctly-rounded f64 -> bf16 (single rounding): round-to-odd to f32, then RNE.
__device__ __forceinline__ float f64_to_bf16_f32(double d) {
    float fz = __double2float_rz(d);
    if ((double)fz != d) {
        unsigned u; __builtin_memcpy(&u, &fz, 4); u |= 1u; __builtin_memcpy(&fz, &u, 4);
    }
    return round_bf16_f32(fz);
}
// Spread the 8 bits of b to positions 0,4,8,...,28 (Morton-4).
__device__ __forceinline__ unsigned spread4(unsigned b) {
    unsigned x = (b | (b << 12)) & 0x000F000Fu;
    x = (x | (x << 6)) & 0x03030303u;
    x = (x | (x << 3)) & 0x11111111u;
    return x;
}

// ---------- dtype detect + init ----------
// fp32 spike words are exactly {0, 0x3F800000}. bf16-pair words hit other
// patterns with P=0.3/word -> P(misclassify bf16 as f32) = 0.7^64 ~ 1e-10.
__global__ void detect_and_init(const unsigned* __restrict__ spk,
                                int* __restrict__ flag, float* __restrict__ sums)
{
    unsigned w = spk[threadIdx.x];
    bool ok = (w == 0u) || (w == 0x3F800000u);
    unsigned long long vote = __ballot(ok);
    if (threadIdx.x == 0) {
        flag[0] = (vote == 0xFFFFFFFFFFFFFFFFull) ? 0 : 1;  // 0=f32, 1=bf16
        sums[0] = 0.f; sums[1] = 0.f; sums[2] = 0.f;
    }
}

// ---------- bit-pack layer-1 input spikes: one u32 mask (T=32) per site ----------
__global__ __launch_bounds__(256)
void pack_input(const void* __restrict__ ginv, unsigned* __restrict__ omask,
                int total, const int* __restrict__ flag)
{
    const int gid = blockIdx.x * 256 + threadIdx.x;
    if (gid >= total) return;
    unsigned mask = 0u;
    if (flag[0]) {
        const uint4* p = (const uint4*)((const unsigned short*)ginv + (size_t)gid * TT);
        #pragma unroll
        for (int q = 0; q < 4; ++q) {
            uint4 a = p[q];
            unsigned wd[4] = {a.x, a.y, a.z, a.w};
            #pragma unroll
            for (int m = 0; m < 4; ++m) {
                const int t = q * 8 + m * 2;
                mask |= (wd[m] & 0xFFFFu) ? (1u << t)       : 0u;
                mask |= (wd[m] >> 16)     ? (1u << (t + 1)) : 0u;
            }
        }
    } else {
        const float4* p = (const float4*)((const float*)ginv + (size_t)gid * TT);
        #pragma unroll
        for (int j = 0; j < 8; ++j) {
            float4 v = p[j];
            mask |= (v.x != 0.f) ? (1u << (j * 4 + 0)) : 0u;
            mask |= (v.y != 0.f) ? (1u << (j * 4 + 1)) : 0u;
            mask |= (v.z != 0.f) ? (1u << (j * 4 + 2)) : 0u;
            mask |= (v.w != 0.f) ? (1u << (j * 4 + 3)) : 0u;
        }
    }
    omask[gid] = mask;
}

// ---------- fused ConvT(stride2,k3,pad1, w*2) + CUBA scan, LDS-LUT inner loop ----------
// Grid: x = site chunk within parity class, y = co, z = parity class (reversed:
// heavy 4-tap class first). Per block (co, tap-set) are uniform, so the 16
// possible f64 partial sums of each 4-cin group are precomputed in LDS; the
// inner loop per t is bfe + ds_read_b64 + v_add_f64 (no f64 pairing movs).
template<int CIN, int COUT, bool LAST>
__global__ __launch_bounds__(256)
void cuba_layer(const unsigned* __restrict__ inMask, const void* __restrict__ wptr,
                void* __restrict__ goutv, unsigned* __restrict__ outMask,
                int N, int Hi, int Wi, float* __restrict__ sumOut,
                const int* __restrict__ flag)
{
    const bool isbf = (flag[0] != 0);
    const int Ho = 2 * Hi - 1, Wo = 2 * Wi - 1;
    const int co = (int)blockIdx.y;
    const int zz = 3 - (int)blockIdx.z;          // heavy class launches first
    const int po = zz >> 1, pw = zz & 1;
    const int nH = Hi - po, nW = Wi - pw;        // #oh / #ow values in this class
    const int spc = N * nH * nW;                 // sites in this class (per co)
    const int gid2 = (int)blockIdx.x * 256 + (int)threadIdx.x;

    const int nTap = (po ? 2 : 1) * (pw ? 2 : 1);
    const int log2nTap = po + pw;
    const int kwA = pw ? 2 : 1;
    const int khA = po ? 2 : 1;

    // LUT[group][tap][idx]: sequential f64 sum of selected 2*w over the 4 cins.
    __shared__ double lut[CIN / 4][4][16];
    {
        const unsigned short* w16 = (const unsigned short*)wptr;
        const float* w32 = (const float*)wptr;
        const int entries = (CIN / 4) * nTap * 16;
        for (int e = threadIdx.x; e < entries; e += 256) {
            const int idx = e & 15;
            const int tp  = (e >> 4) & (nTap - 1);
            const int g   = e >> (4 + log2nTap);
            // tap tp -> (kh,kw): order A,B,C,D
            const int v = (po && (tp >= (pw ? 2 : 1))) ? 1 : 0;
            const int h = pw ? (tp & 1) : 0;
            const int kh = v ? 0 : khA;
            const int kw = h ? 0 : kwA;
            const int wof = kh * 3 + kw;
            double s = 0.0;
            #pragma unroll
            for (int k = 0; k < 4; ++k) {
                if ((idx >> k) & 1) {
                    const int wi = ((4 * g + k) * COUT + co) * 9 + wof;
                    const float wraw = isbf ? bf16_bits_to_f32(w16[wi]) : w32[wi];
                    s += 2.0 * (double)wraw;     // weight_scale=2 folded (exact)
                }
            }
            lut[g][tp][idx] = s;
        }
    }
    __syncthreads();

    float cnt = 0.f;
    if (gid2 < spc) {
        const int b  = gid2 % nW;
        const int t1 = gid2 / nW;
        const int a  = t1 % nH;
        const int n  = t1 / nH;
        const int oh = 2 * a + po, ow = 2 * b + pw;
        const int planeSites = Hi * Wi;

        // Static taps (bounds-safe: po=1 -> a <= Hi-2, pw=1 -> b <= Wi-2).
        const int siteA = a * Wi + b;
        const int siteB = a * Wi + (b + 1);
        const int siteC = (a + 1) * Wi + b;
        const int siteD = (a + 1) * Wi + (b + 1);

        double acc[TT];
        #pragma unroll
        for (int t = 0; t < TT; ++t) acc[t] = 0.0;

        for (int g = 0; g < CIN / 4; ++g) {
            const int sB = (n * CIN + 4 * g) * planeSites;

            auto addTap = [&](int site, int tpIdx) {
                const int s0 = sB + site;
                const unsigned m0 = inMask[s0];
                const unsigned m1 = inMask[s0 + planeSites];
                const unsigned m2 = inMask[s0 + 2 * planeSites];
                const unsigned m3 = inMask[s0 + 3 * planeSites];
                const double* lp = &lut[g][tpIdx][0];
                #pragma unroll
                for (int q = 0; q < 4; ++q) {
                    const unsigned wq =  spread4((m0 >> (8 * q)) & 0xFFu)
                                      | (spread4((m1 >> (8 * q)) & 0xFFu) << 1)
                                      | (spread4((m2 >> (8 * q)) & 0xFFu) << 2)
                                      | (spread4((m3 >> (8 * q)) & 0xFFu) << 3);
                    #pragma unroll
                    for (int j = 0; j < 8; ++j) {
                        const unsigned idx = (wq >> (4 * j)) & 0xFu;
                        acc[q * 8 + j] += lp[idx];
                    }
                }
            };

            addTap(siteA, 0);
            if (pw) addTap(siteB, 1);            // block-uniform branches
            if (po) {
                addTap(siteC, pw ? 2 : 1);
                if (pw) addTap(siteD, 3);
            }
        }

        // CUBA scan.
        unsigned mask = 0u;
        if (isbf) {
            // bf16 semantics: every add rounds to bf16; *0.5 and reset exact.
            float cur = 0.f, vol = 0.f;
            #pragma unroll
            for (int t = 0; t < TT; ++t) {
                const float z = f64_to_bf16_f32(acc[t]);      // conv output in bf16
                cur = round_bf16_f32(0.5f * cur + z);
                vol = round_bf16_f32(0.5f * vol + cur);
                const bool fire = (vol >= 1.0f);
                mask |= fire ? (1u << t) : 0u;
                vol = fire ? 0.f : vol;
            }
        } else {
            double cur = 0.0, vol = 0.0;
            #pragma unroll
            for (int t = 0; t < TT; ++t) {
                cur = fma(0.5, cur, acc[t]);
                vol = fma(0.5, vol, cur);
                const bool fire = (vol >= 1.0);
                mask |= fire ? (1u << t) : 0u;
                vol = fire ? 0.0 : vol;
            }
        }
        cnt = (float)__popc(mask);

        const int gidOut = ((n * COUT + co) * Ho + oh) * Wo + ow;
        if (LAST) {
            if (isbf) {
                uint4* ob = (uint4*)((unsigned short*)goutv + (size_t)gidOut * TT);
                #pragma unroll
                for (int q = 0; q < 4; ++q) {
                    unsigned wd[4];
                    #pragma unroll
                    for (int m2 = 0; m2 < 4; ++m2) {
                        const int t = (q * 4 + m2) * 2;
                        wd[m2] = (((mask >> t) & 1u) ? 0x3F80u : 0u)
                               | (((mask >> (t + 1)) & 1u) ? 0x3F800000u : 0u);
                    }
                    ob[q] = make_uint4(wd[0], wd[1], wd[2], wd[3]);
                }
            } else {
                float4* ob = (float4*)((float*)goutv + (size_t)gidOut * TT);
                #pragma unroll
                for (int j = 0; j < 8; ++j) {
                    float4 s4;
                    s4.x = (mask >> (j * 4 + 0)) & 1u ? 1.0f : 0.0f;
                    s4.y = (mask >> (j * 4 + 1)) & 1u ? 1.0f : 0.0f;
                    s4.z = (mask >> (j * 4 + 2)) & 1u ? 1.0f : 0.0f;
                    s4.w = (mask >> (j * 4 + 3)) & 1u ? 1.0f : 0.0f;
                    ob[j] = s4;
                }
            }
        } else {
            outMask[gidOut] = mask;
        }
    }

    // Wave-level (64) count reduction; per-layer sums are integers < 2^24 so
    // fp32 atomic accumulation is exact.
    #pragma unroll
    for (int o = 32; o >= 1; o >>= 1) cnt += __shfl_down(cnt, o);
    if ((threadIdx.x & 63) == 0 && cnt > 0.f) atomicAdd(sumOut, cnt);
}

__global__ void finalize_counts(const float* __restrict__ sums,
                                void* __restrict__ out, const int* __restrict__ flag)
{
    int i = threadIdx.x;
    if (i < 3) {
        const float numel[3] = {7872512.f, 15239168.f, 3748096.f};
        float v = sums[i] / numel[i];
        if (flag[0]) ((unsigned short*)out)[3748096 + i] = f32_to_bf16_rne(v);
        else         ((float*)out)[3748096 + i] = v;
    }
}

extern "C" void kernel_launch(void* const* d_in, const int* in_sizes, int n_in,
                              void* d_out, int out_size, void* d_ws, size_t ws_size,
                              hipStream_t stream)
{
    const void* x  = d_in[0];  // [4,128,16,16,32] spikes (f32 or bf16)
    const void* w1 = d_in[1];  // [128,64,3,3]
    const void* w2 = d_in[2];  // [64,32,3,3]
    const void* w3 = d_in[3];  // [32,2,3,3]

    // Bit-packed masks: input + both intermediates. Total ws ~ 3.42 MB.
    unsigned* buf0 = (unsigned*)d_ws;          // 4*128*16*16 = 131,072 words
    unsigned* buf1 = buf0 + 131072;            // 4*64*31*31  = 246,016 words
    unsigned* buf2 = buf1 + 246016;            // 4*32*61*61  = 476,288 words
    float* sums = (float*)(buf2 + 476288);     // 3 floats
    int*   flag = (int*)(sums + 3);

    detect_and_init<<<1, 64, 0, stream>>>((const unsigned*)x, flag, sums);
    pack_input<<<512, 256, 0, stream>>>(x, buf0, 131072, flag);

    // Grid: x = site chunk (max class: 4*Hi*Wi sites), y = co, z = parity class.
    // L1: 128->64, 16x16 -> 31x31. ceil(4*16*16/256)=4
    cuba_layer<128, 64, false><<<dim3(4, 64, 4), 256, 0, stream>>>(
        buf0, w1, nullptr, buf1, 4, 16, 16, sums + 0, flag);
    // L2: 64->32, 31x31 -> 61x61. ceil(4*31*31/256)=16
    cuba_layer<64, 32, false><<<dim3(16, 32, 4), 256, 0, stream>>>(
        buf1, w2, nullptr, buf2, 4, 31, 31, sums + 1, flag);
    // L3: 32->2, 61x61 -> 121x121. ceil(4*61*61/256)=59
    cuba_layer<32, 2, true><<<dim3(59, 2, 4), 256, 0, stream>>>(
        buf2, w3, d_out, nullptr, 4, 61, 61, sums + 2, flag);

    finalize_counts<<<1, 64, 0, stream>>>(sums, d_out, flag);
}